// Round 1
// baseline (1421.318 us; speedup 1.0000x reference)
//
#include <hip/hip_runtime.h>
#include <math.h>

#define D_NODE 100
#define D_HID  300
static const int BB = 128, TSEQ = 512, LQn = 256, NNODE = 256;

typedef unsigned int u32;
typedef unsigned short u16;

__device__ __forceinline__ float bflo(u32 u){ return __uint_as_float(u << 16); }
__device__ __forceinline__ float bfhi(u32 u){ return __uint_as_float(u & 0xffff0000u); }
__device__ __forceinline__ u16 f2bf(float f){
    u32 u = __float_as_uint(f);
    return (u16)((u + 0x7fffu + ((u >> 16) & 1u)) >> 16);
}
__device__ __forceinline__ u32 pack_bf(float lo, float hi){
    return ((u32)f2bf(lo)) | (((u32)f2bf(hi)) << 16);
}

// ---------------- K0: fold W_mean/b_mean into GRU input weights ----------------
// W4[dir][k][gate][320] = sum_q Wih[gate*300+j][q] * Wm[q][k]  (j = x index, padded to 320)
// bc[dir][gate][320]    = b_ih + (gate<2 ? b_hh : 0) + Wih . b_mean
// bhhn[dir][320]        = b_hh[600+j]
__global__ __launch_bounds__(128)
void k0_prep(const float* __restrict__ Wm, const float* __restrict__ bm,
             const float* __restrict__ Wihf, const float* __restrict__ bihf, const float* __restrict__ bhhf,
             const float* __restrict__ Wihb, const float* __restrict__ bihb, const float* __restrict__ bhhb,
             float* __restrict__ W4, float* __restrict__ bc, float* __restrict__ bhhn)
{
    int j = blockIdx.x, g = blockIdx.y, dir = blockIdx.z;
    int tid = threadIdx.x;
    const float* Wih = dir ? Wihb : Wihf;
    const float* bih = dir ? bihb : bihf;
    const float* bhh = dir ? bhhb : bhhf;
    if (j >= D_HID) {  // pad region
        for (int k = tid; k < D_NODE; k += 128)
            W4[((size_t)(dir*D_NODE + k)*3 + g)*320 + j] = 0.f;
        if (tid == 0) {
            bc[(dir*3 + g)*320 + j] = 0.f;
            if (g == 2) bhhn[dir*320 + j] = 0.f;
        }
        return;
    }
    const float* wrow = Wih + (size_t)(g*D_HID + j)*D_HID;
    for (int k = tid; k < D_NODE; k += 128) {
        float s = 0.f;
        for (int q = 0; q < D_HID; ++q)
            s = fmaf(wrow[q], Wm[q*D_NODE + k], s);
        W4[((size_t)(dir*D_NODE + k)*3 + g)*320 + j] = s;
    }
    __shared__ float red[128];
    float p = 0.f;
    for (int q = tid; q < D_HID; q += 128) p = fmaf(bm[q], wrow[q], p);
    red[tid] = p;
    __syncthreads();
    for (int off = 64; off > 0; off >>= 1) {
        if (tid < off) red[tid] += red[tid + off];
        __syncthreads();
    }
    if (tid == 0) {
        float base = bih[g*D_HID + j] + red[0];
        if (g < 2) base += bhh[g*D_HID + j];
        bc[(dir*3 + g)*320 + j] = base;
        if (g == 2) bhhn[dir*320 + j] = bhh[2*D_HID + j];
    }
}

// ---------------- K1: gather tri_mean + GEMM(K=100) + GRU epilogue -> H[M,600] bf16 ----------------
// grid: (M/64, 10) ; y -> dir = y/5, j0 = (y%5)*64 ; 256 thr; 4x(4x3) micro-tile
__global__ __launch_bounds__(256)
void k1_gru(const float* __restrict__ nodes, const int* __restrict__ triples,
            const float* __restrict__ W4, const float* __restrict__ bc,
            const float* __restrict__ bhhn, u16* __restrict__ H)
{
    __shared__ float A[20][64];          // [k][token]
    __shared__ float Bsh[20*3*64];       // [k][gate][j]
    __shared__ int hidx[64], tidx[64];
    int tid = threadIdx.x;
    int m0 = blockIdx.x * 64;
    int dir = blockIdx.y / 5;
    int j0 = (blockIdx.y % 5) * 64;
    int b = m0 >> 9;        // / TSEQ (64 | 512 -> uniform b per block)
    int t0 = m0 & 511;
    if (tid < 128) {
        int tok = tid >> 1, w = tid & 1;
        int v = triples[((size_t)b*TSEQ + t0 + tok)*3 + (w ? 2 : 0)];
        if (w) tidx[tok] = v; else hidx[tok] = v;
    }
    __syncthreads();

    float accr[4][4], accz[4][4], accn[4][4];
    #pragma unroll
    for (int i = 0; i < 4; ++i)
        #pragma unroll
        for (int jj = 0; jj < 4; ++jj) { accr[i][jj] = 0.f; accz[i][jj] = 0.f; accn[i][jj] = 0.f; }

    const float* nb = nodes + (size_t)b*NNODE*D_NODE;
    const float* Wbase = W4 + (size_t)dir*D_NODE*3*320 + j0;
    int tx4 = (tid & 15)*4, ty4 = (tid >> 4)*4;

    for (int k0 = 0; k0 < D_NODE; k0 += 20) {
        for (int i = tid; i < 20*64; i += 256) {
            int k = i >> 6, tok = i & 63;
            int kk = k0 + k;
            A[k][tok] = 0.5f*(nb[(size_t)hidx[tok]*D_NODE + kk] + nb[(size_t)tidx[tok]*D_NODE + kk]);
        }
        for (int i = tid; i < 20*192; i += 256) {
            int row = i >> 6, col = i & 63;      // row = k*3+g
            Bsh[i] = Wbase[(size_t)(k0*3 + row)*320 + col];
        }
        __syncthreads();
        #pragma unroll
        for (int k = 0; k < 20; ++k) {
            float4 a  = *(const float4*)&A[k][ty4];
            float4 br = *(const float4*)&Bsh[(k*3+0)*64 + tx4];
            float4 bz = *(const float4*)&Bsh[(k*3+1)*64 + tx4];
            float4 bn = *(const float4*)&Bsh[(k*3+2)*64 + tx4];
            float av[4]  = {a.x, a.y, a.z, a.w};
            float brv[4] = {br.x, br.y, br.z, br.w};
            float bzv[4] = {bz.x, bz.y, bz.z, bz.w};
            float bnv[4] = {bn.x, bn.y, bn.z, bn.w};
            #pragma unroll
            for (int t = 0; t < 4; ++t)
                #pragma unroll
                for (int jj = 0; jj < 4; ++jj) {
                    accr[t][jj] = fmaf(av[t], brv[jj], accr[t][jj]);
                    accz[t][jj] = fmaf(av[t], bzv[jj], accz[t][jj]);
                    accn[t][jj] = fmaf(av[t], bnv[jj], accn[t][jj]);
                }
        }
        __syncthreads();
    }
    #pragma unroll
    for (int jj = 0; jj < 4; ++jj) {
        int j = j0 + tx4 + jj;
        if (j >= D_HID) continue;
        float bcr = bc[(dir*3+0)*320 + j];
        float bcz = bc[(dir*3+1)*320 + j];
        float bcn = bc[(dir*3+2)*320 + j];
        float bn2 = bhhn[dir*320 + j];
        #pragma unroll
        for (int t = 0; t < 4; ++t) {
            float r = 1.f/(1.f + __expf(-(accr[t][jj] + bcr)));
            float z = 1.f/(1.f + __expf(-(accz[t][jj] + bcz)));
            float n = tanhf(accn[t][jj] + bcn + r*bn2);
            float h = (1.f - z)*n;
            H[(size_t)(m0 + (tid>>4)*4 + t)*600 + dir*D_HID + j] = f2bf(h);
        }
    }
}

// ---------------- K2: Hid = tanh(H @ Wout^T + bout), K=600 -> bf16 [M,300] ----------------
__global__ __launch_bounds__(256)
void k2_out(const u16* __restrict__ H, const float* __restrict__ Wout,
            const float* __restrict__ bout, u16* __restrict__ Hid)
{
    __shared__ float A[40][68];
    __shared__ float Bs[40][68];
    int tid = threadIdx.x;
    int m0 = blockIdx.x * 64;
    int c0 = blockIdx.y * 64;
    float acc[4][4];
    #pragma unroll
    for (int i = 0; i < 4; ++i)
        #pragma unroll
        for (int j = 0; j < 4; ++j) acc[i][j] = 0.f;
    int tx4 = (tid & 15)*4, ty4 = (tid >> 4)*4;

    for (int k0 = 0; k0 < 600; k0 += 40) {
        for (int i = tid; i < 1280; i += 256) {
            int tok = i / 20, kk = (i % 20)*2;
            u32 u = *(const u32*)&H[(size_t)(m0+tok)*600 + k0 + kk];
            A[kk][tok]   = bflo(u);
            A[kk+1][tok] = bfhi(u);
        }
        for (int i = tid; i < 2560; i += 256) {
            int c = i / 40, k = i % 40;
            int cg = c0 + c;
            Bs[k][c] = (cg < D_HID) ? Wout[(size_t)cg*600 + k0 + k] : 0.f;
        }
        __syncthreads();
        #pragma unroll
        for (int k = 0; k < 40; ++k) {
            float4 a  = *(const float4*)&A[k][ty4];
            float4 bb = *(const float4*)&Bs[k][tx4];
            float av[4] = {a.x, a.y, a.z, a.w};
            float bv[4] = {bb.x, bb.y, bb.z, bb.w};
            #pragma unroll
            for (int t = 0; t < 4; ++t)
                #pragma unroll
                for (int cc = 0; cc < 4; ++cc)
                    acc[t][cc] = fmaf(av[t], bv[cc], acc[t][cc]);
        }
        __syncthreads();
    }
    #pragma unroll
    for (int cc = 0; cc < 4; ++cc) {
        int c = c0 + tx4 + cc;
        if (c >= D_HID) continue;
        float bo = bout[c];
        #pragma unroll
        for (int t = 0; t < 4; ++t)
            Hid[(size_t)(m0 + ty4 + t)*300 + c] = f2bf(tanhf(acc[t][cc] + bo));
    }
}

// ---------------- K3: scores = ctx @ Hid^T, softmax over t, alpha += sum_l ----------------
// grid (8, B); 256 thr; per block: 32 queries x all 512 t; scores live in packed-bf16 VGPRs
__global__ __launch_bounds__(256)
void k3_attn(const float* __restrict__ ctx, const u16* __restrict__ Hid,
             float* __restrict__ alpha)
{
    __shared__ u32 C2[300][20];     // [k][l-pair], bf16x2 (24,000 B)
    __shared__ float Hs[12][132];   // [k][t] (6,336 B)
    int tid = threadIdx.x;
    int l0 = blockIdx.x * 32;
    int b = blockIdx.y;
    for (int i = tid; i < 4800; i += 256) {
        int lp = i / 300, k = i % 300;
        const float* cp = ctx + ((size_t)b*LQn + l0 + lp*2)*D_HID + k;
        C2[k][lp] = pack_bf(cp[0], cp[D_HID]);
    }
    int tx = tid & 31, ty = tid >> 5;   // tx: 4 t's; ty: 4 l's (32-lane shuffle group == ty)
    u32 sreg[4][8];                     // [chunk][il*2+w] packed scores
    for (int ch = 0; ch < 4; ++ch) {
        float acc[4][4];
        #pragma unroll
        for (int i = 0; i < 4; ++i)
            #pragma unroll
            for (int j = 0; j < 4; ++j) acc[i][j] = 0.f;
        const u16* hb = Hid + ((size_t)b*TSEQ + ch*128)*D_HID;
        for (int k0 = 0; k0 < 300; k0 += 12) {
            for (int i = tid; i < 768; i += 256) {
                int t = i / 6, kk = (i % 6)*2;
                u32 u = *(const u32*)&hb[(size_t)t*D_HID + k0 + kk];
                Hs[kk][t]   = bflo(u);
                Hs[kk+1][t] = bfhi(u);
            }
            __syncthreads();
            #pragma unroll
            for (int k = 0; k < 12; ++k) {
                uint2 cu = *(const uint2*)&C2[k0+k][ty*2];
                float4 hv = *(const float4*)&Hs[k][tx*4];
                float cv[4]  = {bflo(cu.x), bfhi(cu.x), bflo(cu.y), bfhi(cu.y)};
                float hvv[4] = {hv.x, hv.y, hv.z, hv.w};
                #pragma unroll
                for (int il = 0; il < 4; ++il)
                    #pragma unroll
                    for (int it = 0; it < 4; ++it)
                        acc[il][it] = fmaf(cv[il], hvv[it], acc[il][it]);
            }
            __syncthreads();
        }
        #pragma unroll
        for (int il = 0; il < 4; ++il) {
            sreg[ch][il*2]   = pack_bf(acc[il][0], acc[il][1]);
            sreg[ch][il*2+1] = pack_bf(acc[il][2], acc[il][3]);
        }
    }
    float mrow[4], inv[4];
    #pragma unroll
    for (int il = 0; il < 4; ++il) {
        float m = -1e30f;
        #pragma unroll
        for (int ch = 0; ch < 4; ++ch) {
            u32 w0 = sreg[ch][il*2], w1 = sreg[ch][il*2+1];
            m = fmaxf(m, fmaxf(fmaxf(bflo(w0), bfhi(w0)), fmaxf(bflo(w1), bfhi(w1))));
        }
        #pragma unroll
        for (int off = 16; off > 0; off >>= 1) m = fmaxf(m, __shfl_xor(m, off, 32));
        float s = 0.f;
        #pragma unroll
        for (int ch = 0; ch < 4; ++ch) {
            u32 w0 = sreg[ch][il*2], w1 = sreg[ch][il*2+1];
            s += __expf(bflo(w0) - m) + __expf(bfhi(w0) - m)
               + __expf(bflo(w1) - m) + __expf(bfhi(w1) - m);
        }
        #pragma unroll
        for (int off = 16; off > 0; off >>= 1) s += __shfl_xor(s, off, 32);
        mrow[il] = m; inv[il] = 1.f / s;
    }
    float* ab = alpha + (size_t)b*TSEQ;
    #pragma unroll
    for (int ch = 0; ch < 4; ++ch) {
        float pt[4] = {0.f, 0.f, 0.f, 0.f};
        #pragma unroll
        for (int il = 0; il < 4; ++il) {
            u32 w0 = sreg[ch][il*2], w1 = sreg[ch][il*2+1];
            float sc = inv[il];
            pt[0] += __expf(bflo(w0) - mrow[il]) * sc;
            pt[1] += __expf(bfhi(w0) - mrow[il]) * sc;
            pt[2] += __expf(bflo(w1) - mrow[il]) * sc;
            pt[3] += __expf(bfhi(w1) - mrow[il]) * sc;
        }
        int tb = ch*128 + tx*4;
        atomicAdd(&ab[tb+0], pt[0]);
        atomicAdd(&ab[tb+1], pt[1]);
        atomicAdd(&ab[tb+2], pt[2]);
        atomicAdd(&ab[tb+3], pt[3]);
    }
}

// ---------------- K4: rep = alpha @ Hid ; layernorm -> path_feature ----------------
__global__ __launch_bounds__(320)
void k4_rep(const float* __restrict__ alpha, const u16* __restrict__ Hid,
            const float* __restrict__ gamma, const float* __restrict__ beta,
            float* __restrict__ outP)
{
    __shared__ float al[512];
    __shared__ float rs[5], rss[5];
    int tid = threadIdx.x, b = blockIdx.x;
    for (int i = tid; i < 512; i += 320) al[i] = alpha[(size_t)b*TSEQ + i];
    __syncthreads();
    float acc = 0.f;
    if (tid < D_HID) {
        const u16* hp = Hid + (size_t)b*TSEQ*D_HID + tid;
        #pragma unroll 8
        for (int t = 0; t < TSEQ; ++t)
            acc = fmaf(al[t], bflo((u32)hp[(size_t)t*D_HID]), acc);
    }
    float v = (tid < D_HID) ? acc : 0.f;
    float s = v, q = v*v;
    #pragma unroll
    for (int off = 32; off > 0; off >>= 1) { s += __shfl_xor(s, off, 64); q += __shfl_xor(q, off, 64); }
    if ((tid & 63) == 0) { rs[tid >> 6] = s; rss[tid >> 6] = q; }
    __syncthreads();
    float S = rs[0]+rs[1]+rs[2]+rs[3]+rs[4];
    float Q = rss[0]+rss[1]+rss[2]+rss[3]+rss[4];
    float mu = S * (1.f/300.f);
    float var = Q * (1.f/300.f) - mu*mu;
    if (tid < D_HID)
        outP[(size_t)b*D_HID + tid] = (acc - mu) * rsqrtf(var + 1e-5f) * gamma[tid] + beta[tid];
}

// ---------------- K5: node_feature = nodes @ Wnode^T + bnode (fp32) ----------------
__global__ __launch_bounds__(256)
void k5_node(const float* __restrict__ nodes, const float* __restrict__ Wn,
             const float* __restrict__ bn, float* __restrict__ outN)
{
    __shared__ float A[20][68];
    __shared__ float Bs[20][68];
    int tid = threadIdx.x;
    int m0 = blockIdx.x * 64;
    int c0 = blockIdx.y * 64;
    float acc[4][4];
    #pragma unroll
    for (int i = 0; i < 4; ++i)
        #pragma unroll
        for (int j = 0; j < 4; ++j) acc[i][j] = 0.f;
    int tx4 = (tid & 15)*4, ty4 = (tid >> 4)*4;

    for (int k0 = 0; k0 < D_NODE; k0 += 20) {
        for (int i = tid; i < 1280; i += 256) {
            int tok = i / 20, k = i % 20;
            A[k][tok] = nodes[(size_t)(m0+tok)*D_NODE + k0 + k];
        }
        for (int i = tid; i < 1280; i += 256) {
            int c = i / 20, k = i % 20;
            int cg = c0 + c;
            Bs[k][c] = (cg < D_HID) ? Wn[(size_t)cg*D_NODE + k0 + k] : 0.f;
        }
        __syncthreads();
        #pragma unroll
        for (int k = 0; k < 20; ++k) {
            float4 a  = *(const float4*)&A[k][ty4];
            float4 bb = *(const float4*)&Bs[k][tx4];
            float av[4] = {a.x, a.y, a.z, a.w};
            float bv[4] = {bb.x, bb.y, bb.z, bb.w};
            #pragma unroll
            for (int t = 0; t < 4; ++t)
                #pragma unroll
                for (int cc = 0; cc < 4; ++cc)
                    acc[t][cc] = fmaf(av[t], bv[cc], acc[t][cc]);
        }
        __syncthreads();
    }
    #pragma unroll
    for (int cc = 0; cc < 4; ++cc) {
        int c = c0 + tx4 + cc;
        if (c >= D_HID) continue;
        float bo = bn[c];
        #pragma unroll
        for (int t = 0; t < 4; ++t)
            outN[(size_t)(m0 + ty4 + t)*300 + c] = acc[t][cc] + bo;
    }
}

extern "C" void kernel_launch(void* const* d_in, const int* in_sizes, int n_in,
                              void* d_out, int out_size, void* d_ws, size_t ws_size,
                              hipStream_t stream) {
    const float* nodes  = (const float*)d_in[0];
    const float* ctx    = (const float*)d_in[1];
    const int*   trip   = (const int*)d_in[2];
    const float* Wm     = (const float*)d_in[4];
    const float* bm     = (const float*)d_in[5];
    const float* Wihf   = (const float*)d_in[6];
    const float* bihf   = (const float*)d_in[7];
    const float* bhhf   = (const float*)d_in[8];
    const float* Wihb   = (const float*)d_in[9];
    const float* bihb   = (const float*)d_in[10];
    const float* bhhb   = (const float*)d_in[11];
    const float* Wout   = (const float*)d_in[12];
    const float* bout   = (const float*)d_in[13];
    const float* Wnode  = (const float*)d_in[14];
    const float* bnode  = (const float*)d_in[15];
    const float* gamma  = (const float*)d_in[16];
    const float* beta   = (const float*)d_in[17];
    float* out = (float*)d_out;

    char* ws = (char*)d_ws;
    float* W4   = (float*)ws;                                  // 192,000 f
    float* bc   = W4 + 192000;                                 // 1,920 f
    float* bhhn = bc + 1920;                                   // 640 f
    size_t off = (size_t)(192000 + 1920 + 640) * 4;            // 778,240 B
    u16* H    = (u16*)(ws + off);                              // 65536*600 bf16
    u16* Hid  = (u16*)(ws + off + 78643200ull);                // 65536*300 bf16
    float* alpha = (float*)(ws + off + 78643200ull + 39321600ull); // 65536 f
    // total ws usage: 119,005,184 B

    hipMemsetAsync(alpha, 0, 65536*sizeof(float), stream);

    k0_prep<<<dim3(320,3,2), 128, 0, stream>>>(Wm,bm,Wihf,bihf,bhhf,Wihb,bihb,bhhb,W4,bc,bhhn);
    k1_gru <<<dim3(1024,10), 256, 0, stream>>>(nodes,trip,W4,bc,bhhn,H);
    k2_out <<<dim3(1024,5),  256, 0, stream>>>(H,Wout,bout,Hid);
    k3_attn<<<dim3(8,128),   256, 0, stream>>>(ctx,Hid,alpha);
    k4_rep <<<128,           320, 0, stream>>>(alpha,Hid,gamma,beta,out);
    k5_node<<<dim3(512,5),   256, 0, stream>>>(nodes,Wnode,bnode,out + 38400);
    // node_mask: zeros (bool -> 0.0f)
    hipMemsetAsync(out + 38400 + 9830400, 0, 32768*sizeof(float), stream);
}

// Round 2
// 758.299 us; speedup vs baseline: 1.8743x; 1.8743x over previous
//
#include <hip/hip_runtime.h>
#include <math.h>

#define D_NODE 100
#define D_HID  300
static const int TSEQ = 512, LQn = 256, NNODE = 256;

typedef unsigned int u32;
typedef unsigned short u16;
typedef __attribute__((ext_vector_type(8))) short bf16x8;   // 8 bf16 = 4 VGPRs
typedef __attribute__((ext_vector_type(4))) float f32x4;

__device__ __forceinline__ float bflo(u32 u){ return __uint_as_float(u << 16); }
__device__ __forceinline__ float bfhi(u32 u){ return __uint_as_float(u & 0xffff0000u); }
__device__ __forceinline__ u16 f2bf(float f){
    u32 u = __float_as_uint(f);
    return (u16)((u + 0x7fffu + ((u >> 16) & 1u)) >> 16);
}
__device__ __forceinline__ u32 pack_bf(float lo, float hi){
    return ((u32)f2bf(lo)) | (((u32)f2bf(hi)) << 16);
}
__device__ __forceinline__ void gload_lds16(const void* g, void* l){
    __builtin_amdgcn_global_load_lds(
        (const __attribute__((address_space(1))) u32*)g,
        (__attribute__((address_space(3))) u32*)l, 16, 0, 0);
}

// ---------------- K0: fold W_mean into GRU weights -> W4bf bf16 [dir][gate][320 j][128 k] ----------------
__global__ __launch_bounds__(128)
void k0_prep(const float* __restrict__ Wm, const float* __restrict__ bm,
             const float* __restrict__ Wihf, const float* __restrict__ bihf, const float* __restrict__ bhhf,
             const float* __restrict__ Wihb, const float* __restrict__ bihb, const float* __restrict__ bhhb,
             u16* __restrict__ W4bf, float* __restrict__ bc, float* __restrict__ bhhn)
{
    int j = blockIdx.x, g = blockIdx.y, dir = blockIdx.z;
    int tid = threadIdx.x;
    u16* wout = W4bf + ((size_t)((dir*3+g)*320 + j))*128;
    if (j >= D_HID) {
        wout[tid] = 0;
        if (tid == 0) { bc[(dir*3+g)*320 + j] = 0.f; if (g==2) bhhn[dir*320+j] = 0.f; }
        return;
    }
    const float* Wih = dir ? Wihb : Wihf;
    const float* bih = dir ? bihb : bihf;
    const float* bhh = dir ? bhhb : bhhf;
    const float* wrow = Wih + (size_t)(g*D_HID + j)*D_HID;
    int k = tid;
    float s = 0.f;
    if (k < D_NODE)
        for (int q = 0; q < D_HID; ++q)
            s = fmaf(wrow[q], Wm[q*D_NODE + k], s);
    wout[k] = f2bf(k < D_NODE ? s : 0.f);

    __shared__ float red[128];
    float p = 0.f;
    for (int q = tid; q < D_HID; q += 128) p = fmaf(bm[q], wrow[q], p);
    red[tid] = p;
    __syncthreads();
    for (int off = 64; off > 0; off >>= 1) {
        if (tid < off) red[tid] += red[tid + off];
        __syncthreads();
    }
    if (tid == 0) {
        float base = bih[g*D_HID + j] + red[0];
        if (g < 2) base += bhh[g*D_HID + j];
        bc[(dir*3+g)*320 + j] = base;
        if (g == 2) bhhn[dir*320 + j] = bhh[2*D_HID + j];
    }
}

// ---------------- KW: convert Wout -> [384][608] bf16, Wnode -> [320][128] bf16 (zero-padded) ----------------
__global__ __launch_bounds__(256)
void kW(const float* __restrict__ Wout, const float* __restrict__ Wnode,
        u16* __restrict__ Woutbf, u16* __restrict__ Wnbf)
{
    int idx = blockIdx.x*256 + threadIdx.x;
    if (idx < 384*608) {
        int j = idx / 608, k = idx % 608;
        float v = (j < D_HID && k < 600) ? Wout[(size_t)j*600 + k] : 0.f;
        Woutbf[idx] = f2bf(v);
    } else {
        int i2 = idx - 384*608;
        if (i2 < 320*128) {
            int j = i2 >> 7, k = i2 & 127;
            float v = (j < D_HID && k < D_NODE) ? Wnode[(size_t)j*D_NODE + k] : 0.f;
            Wnbf[i2] = f2bf(v);
        }
    }
}

// ---------------- KA: gather+mean -> Abf bf16 [65536][128]; nodes -> Nbf bf16 [32768][128]; zero H pad cols ----------------
__global__ __launch_bounds__(256)
void kA(const float* __restrict__ nodes, const int* __restrict__ trip,
        u32* __restrict__ Abf, u32* __restrict__ Nbf, u16* __restrict__ H)
{
    int gid = blockIdx.x*256 + threadIdx.x;
    if (gid < 65536) {
        int b = gid >> 9;
        int hidx = trip[(size_t)gid*3];
        int tidx = trip[(size_t)gid*3 + 2];
        const float4* nh = (const float4*)(nodes + ((size_t)b*NNODE + hidx)*D_NODE);
        const float4* nt = (const float4*)(nodes + ((size_t)b*NNODE + tidx)*D_NODE);
        u32* ar = Abf + (size_t)gid*64;
        #pragma unroll 5
        for (int i = 0; i < 25; ++i) {
            float4 a = nh[i], c = nt[i];
            ar[i*2]   = pack_bf(0.5f*(a.x+c.x), 0.5f*(a.y+c.y));
            ar[i*2+1] = pack_bf(0.5f*(a.z+c.z), 0.5f*(a.w+c.w));
        }
        #pragma unroll
        for (int i = 50; i < 64; ++i) ar[i] = 0;
        *(uint4*)(H + (size_t)gid*608 + 600) = make_uint4(0,0,0,0);
    } else {
        int r = gid - 65536;
        if (r < 32768) {
            const float4* nr = (const float4*)(nodes + (size_t)r*D_NODE);
            u32* ar = Nbf + (size_t)r*64;
            #pragma unroll 5
            for (int i = 0; i < 25; ++i) {
                float4 a = nr[i];
                ar[i*2]   = pack_bf(a.x, a.y);
                ar[i*2+1] = pack_bf(a.z, a.w);
            }
            #pragma unroll
            for (int i = 50; i < 64; ++i) ar[i] = 0;
        }
    }
}

// ---------------- K1: MFMA GEMM + GRU epilogue -> H[M][608] bf16 ----------------
// grid (1024, 10): y -> dir = y/5, jgroup = y%5. 256 thr = 4 waves; wave w -> 16 j, 3 gates.
__global__ __launch_bounds__(256)
void k1_gru(const u16* __restrict__ Abf, const u16* __restrict__ W4bf,
            const float* __restrict__ bc, const float* __restrict__ bhhn,
            u16* __restrict__ H)
{
    __shared__ char smem[16384];   // 4 msub x 4 ks x 64 lanes x 16 B (fragment order)
    int tid = threadIdx.x;
    int lane = tid & 63, w = tid >> 6;
    int l15 = lane & 15, lq = lane >> 4;
    int m0 = blockIdx.x * 64;
    int dir = blockIdx.y / 5;
    int jg = blockIdx.y % 5;
    int j0w = jg*64 + w*16;

    // B fragments resident: [gate][kstep]
    bf16x8 bfr[3][4];
    const u16* Wb = W4bf + (size_t)dir*3*320*128;
    #pragma unroll
    for (int g = 0; g < 3; ++g)
        #pragma unroll
        for (int ks = 0; ks < 4; ++ks)
            bfr[g][ks] = *(const bf16x8*)(Wb + ((size_t)(g*320 + j0w + l15))*128 + ks*32 + lq*8);

    // stage A in fragment order: wave w stages msub=w, ks 0..3
    #pragma unroll
    for (int ks = 0; ks < 4; ++ks) {
        const u16* g = Abf + ((size_t)(m0 + w*16 + l15))*128 + ks*32 + lq*8;
        gload_lds16(g, smem + (size_t)((w*4 + ks)*64)*16);
    }
    __syncthreads();

    f32x4 acc[4][3];
    #pragma unroll
    for (int ms = 0; ms < 4; ++ms)
        #pragma unroll
        for (int g = 0; g < 3; ++g)
            acc[ms][g] = (f32x4){0.f,0.f,0.f,0.f};

    #pragma unroll
    for (int ms = 0; ms < 4; ++ms)
        #pragma unroll
        for (int ks = 0; ks < 4; ++ks) {
            bf16x8 a = *(const bf16x8*)(smem + (size_t)(((ms*4+ks)*64 + lane))*16);
            acc[ms][0] = __builtin_amdgcn_mfma_f32_16x16x32_bf16(a, bfr[0][ks], acc[ms][0], 0,0,0);
            acc[ms][1] = __builtin_amdgcn_mfma_f32_16x16x32_bf16(a, bfr[1][ks], acc[ms][1], 0,0,0);
            acc[ms][2] = __builtin_amdgcn_mfma_f32_16x16x32_bf16(a, bfr[2][ks], acc[ms][2], 0,0,0);
        }

    int j = j0w + l15;
    float bcr = bc[(dir*3+0)*320 + j];
    float bcz = bc[(dir*3+1)*320 + j];
    float bcn = bc[(dir*3+2)*320 + j];
    float bn2 = bhhn[dir*320 + j];
    bool ok = (j < D_HID);
    #pragma unroll
    for (int ms = 0; ms < 4; ++ms)
        #pragma unroll
        for (int i = 0; i < 4; ++i) {
            float r = 1.f/(1.f + __expf(-(acc[ms][0][i] + bcr)));
            float z = 1.f/(1.f + __expf(-(acc[ms][1][i] + bcz)));
            float n = tanhf(acc[ms][2][i] + bcn + r*bn2);
            float h = (1.f - z)*n;
            if (ok) H[(size_t)(m0 + ms*16 + lq*4 + i)*608 + dir*D_HID + j] = f2bf(h);
        }
}

// ---------------- K2: Hid = tanh(H @ Wout^T + bout) via MFMA -> bf16 [M][300] ----------------
// grid (1024, 3): j0 = y*128; wave w -> j tiles {j0+16w, j0+64+16w}; K = 608 (19 ksteps)
__global__ __launch_bounds__(256, 2)
void k2_out(const u16* __restrict__ H, const u16* __restrict__ Woutbf,
            const float* __restrict__ bout, u16* __restrict__ Hid)
{
    __shared__ char smem[40960];   // 4 msub x 10 ks x 64 x 16 B
    int tid = threadIdx.x;
    int lane = tid & 63, w = tid >> 6;
    int l15 = lane & 15, lq = lane >> 4;
    int m0 = blockIdx.x * 64;
    int j0 = blockIdx.y * 128;
    int jA = j0 + w*16, jB = j0 + 64 + w*16;

    bf16x8 bA[19], bB[19];
    #pragma unroll
    for (int ks = 0; ks < 19; ++ks) {
        bA[ks] = *(const bf16x8*)(Woutbf + ((size_t)(jA + l15))*608 + ks*32 + lq*8);
        bB[ks] = *(const bf16x8*)(Woutbf + ((size_t)(jB + l15))*608 + ks*32 + lq*8);
    }
    f32x4 acc[4][2];
    #pragma unroll
    for (int ms = 0; ms < 4; ++ms) { acc[ms][0] = (f32x4){0,0,0,0}; acc[ms][1] = (f32x4){0,0,0,0}; }

    #pragma unroll
    for (int c = 0; c < 2; ++c) {
        const int kb = c ? 10 : 0;
        const int nks = c ? 9 : 10;
        #pragma unroll
        for (int kk = 0; kk < 10; ++kk)
            if (kk < nks) {
                const u16* g = H + ((size_t)(m0 + w*16 + l15))*608 + (kb+kk)*32 + lq*8;
                gload_lds16(g, smem + (size_t)((w*10 + kk)*64)*16);
            }
        __syncthreads();
        #pragma unroll
        for (int ms = 0; ms < 4; ++ms)
            #pragma unroll
            for (int kk = 0; kk < 10; ++kk)
                if (kk < nks) {
                    bf16x8 a = *(const bf16x8*)(smem + (size_t)(((ms*10+kk)*64 + lane))*16);
                    acc[ms][0] = __builtin_amdgcn_mfma_f32_16x16x32_bf16(a, bA[kb+kk], acc[ms][0], 0,0,0);
                    acc[ms][1] = __builtin_amdgcn_mfma_f32_16x16x32_bf16(a, bB[kb+kk], acc[ms][1], 0,0,0);
                }
        __syncthreads();
    }

    #pragma unroll
    for (int jj = 0; jj < 2; ++jj) {
        int j = (jj ? jB : jA) + l15;
        if (j < D_HID) {
            float bo = bout[j];
            #pragma unroll
            for (int ms = 0; ms < 4; ++ms)
                #pragma unroll
                for (int i = 0; i < 4; ++i)
                    Hid[(size_t)(m0 + ms*16 + lq*4 + i)*D_HID + j] = f2bf(tanhf(acc[ms][jj][i] + bo));
        }
    }
}

// ---------------- K3: scores = ctx @ Hid^T, softmax over t, alpha += sum_l (unchanged) ----------------
__global__ __launch_bounds__(256)
void k3_attn(const float* __restrict__ ctx, const u16* __restrict__ Hid,
             float* __restrict__ alpha)
{
    __shared__ u32 C2[300][20];
    __shared__ float Hs[12][132];
    int tid = threadIdx.x;
    int l0 = blockIdx.x * 32;
    int b = blockIdx.y;
    for (int i = tid; i < 4800; i += 256) {
        int lp = i / 300, k = i % 300;
        const float* cp = ctx + ((size_t)b*LQn + l0 + lp*2)*D_HID + k;
        C2[k][lp] = pack_bf(cp[0], cp[D_HID]);
    }
    int tx = tid & 31, ty = tid >> 5;
    u32 sreg[4][8];
    for (int ch = 0; ch < 4; ++ch) {
        float acc[4][4];
        #pragma unroll
        for (int i = 0; i < 4; ++i)
            #pragma unroll
            for (int j = 0; j < 4; ++j) acc[i][j] = 0.f;
        const u16* hb = Hid + ((size_t)b*TSEQ + ch*128)*D_HID;
        for (int k0 = 0; k0 < 300; k0 += 12) {
            for (int i = tid; i < 768; i += 256) {
                int t = i / 6, kk = (i % 6)*2;
                u32 u = *(const u32*)&hb[(size_t)t*D_HID + k0 + kk];
                Hs[kk][t]   = bflo(u);
                Hs[kk+1][t] = bfhi(u);
            }
            __syncthreads();
            #pragma unroll
            for (int k = 0; k < 12; ++k) {
                uint2 cu = *(const uint2*)&C2[k0+k][ty*2];
                float4 hv = *(const float4*)&Hs[k][tx*4];
                float cv[4]  = {bflo(cu.x), bfhi(cu.x), bflo(cu.y), bfhi(cu.y)};
                float hvv[4] = {hv.x, hv.y, hv.z, hv.w};
                #pragma unroll
                for (int il = 0; il < 4; ++il)
                    #pragma unroll
                    for (int it = 0; it < 4; ++it)
                        acc[il][it] = fmaf(cv[il], hvv[it], acc[il][it]);
            }
            __syncthreads();
        }
        #pragma unroll
        for (int il = 0; il < 4; ++il) {
            sreg[ch][il*2]   = pack_bf(acc[il][0], acc[il][1]);
            sreg[ch][il*2+1] = pack_bf(acc[il][2], acc[il][3]);
        }
    }
    float mrow[4], inv[4];
    #pragma unroll
    for (int il = 0; il < 4; ++il) {
        float m = -1e30f;
        #pragma unroll
        for (int ch = 0; ch < 4; ++ch) {
            u32 w0 = sreg[ch][il*2], w1 = sreg[ch][il*2+1];
            m = fmaxf(m, fmaxf(fmaxf(bflo(w0), bfhi(w0)), fmaxf(bflo(w1), bfhi(w1))));
        }
        #pragma unroll
        for (int off = 16; off > 0; off >>= 1) m = fmaxf(m, __shfl_xor(m, off, 32));
        float s = 0.f;
        #pragma unroll
        for (int ch = 0; ch < 4; ++ch) {
            u32 w0 = sreg[ch][il*2], w1 = sreg[ch][il*2+1];
            s += __expf(bflo(w0) - m) + __expf(bfhi(w0) - m)
               + __expf(bflo(w1) - m) + __expf(bfhi(w1) - m);
        }
        #pragma unroll
        for (int off = 16; off > 0; off >>= 1) s += __shfl_xor(s, off, 32);
        mrow[il] = m; inv[il] = 1.f / s;
    }
    float* ab = alpha + (size_t)b*TSEQ;
    #pragma unroll
    for (int ch = 0; ch < 4; ++ch) {
        float pt[4] = {0.f, 0.f, 0.f, 0.f};
        #pragma unroll
        for (int il = 0; il < 4; ++il) {
            u32 w0 = sreg[ch][il*2], w1 = sreg[ch][il*2+1];
            float sc = inv[il];
            pt[0] += __expf(bflo(w0) - mrow[il]) * sc;
            pt[1] += __expf(bfhi(w0) - mrow[il]) * sc;
            pt[2] += __expf(bflo(w1) - mrow[il]) * sc;
            pt[3] += __expf(bfhi(w1) - mrow[il]) * sc;
        }
        int tb = ch*128 + tx*4;
        atomicAdd(&ab[tb+0], pt[0]);
        atomicAdd(&ab[tb+1], pt[1]);
        atomicAdd(&ab[tb+2], pt[2]);
        atomicAdd(&ab[tb+3], pt[3]);
    }
}

// ---------------- K4: rep = alpha @ Hid ; layernorm -> path_feature (unchanged) ----------------
__global__ __launch_bounds__(320)
void k4_rep(const float* __restrict__ alpha, const u16* __restrict__ Hid,
            const float* __restrict__ gamma, const float* __restrict__ beta,
            float* __restrict__ outP)
{
    __shared__ float al[512];
    __shared__ float rs[5], rss[5];
    int tid = threadIdx.x, b = blockIdx.x;
    for (int i = tid; i < 512; i += 320) al[i] = alpha[(size_t)b*TSEQ + i];
    __syncthreads();
    float acc = 0.f;
    if (tid < D_HID) {
        const u16* hp = Hid + (size_t)b*TSEQ*D_HID + tid;
        #pragma unroll 8
        for (int t = 0; t < TSEQ; ++t)
            acc = fmaf(al[t], bflo((u32)hp[(size_t)t*D_HID]), acc);
    }
    float v = (tid < D_HID) ? acc : 0.f;
    float s = v, q = v*v;
    #pragma unroll
    for (int off = 32; off > 0; off >>= 1) { s += __shfl_xor(s, off, 64); q += __shfl_xor(q, off, 64); }
    if ((tid & 63) == 0) { rs[tid >> 6] = s; rss[tid >> 6] = q; }
    __syncthreads();
    float S = rs[0]+rs[1]+rs[2]+rs[3]+rs[4];
    float Q = rss[0]+rss[1]+rss[2]+rss[3]+rss[4];
    float mu = S * (1.f/300.f);
    float var = Q * (1.f/300.f) - mu*mu;
    if (tid < D_HID)
        outP[(size_t)b*D_HID + tid] = (acc - mu) * rsqrtf(var + 1e-5f) * gamma[tid] + beta[tid];
}

// ---------------- K5: node_feature = nodes @ Wnode^T + bnode via MFMA (fp32 out) ----------------
__global__ __launch_bounds__(256)
void k5_node(const u16* __restrict__ Nbf, const u16* __restrict__ Wnbf,
             const float* __restrict__ bn, float* __restrict__ outN)
{
    __shared__ char smem[16384];
    int tid = threadIdx.x;
    int lane = tid & 63, w = tid >> 6;
    int l15 = lane & 15, lq = lane >> 4;
    int m0 = blockIdx.x * 64;
    int j0w = blockIdx.y*64 + w*16;

    bf16x8 bw[4];
    #pragma unroll
    for (int ks = 0; ks < 4; ++ks)
        bw[ks] = *(const bf16x8*)(Wnbf + ((size_t)(j0w + l15))*128 + ks*32 + lq*8);

    #pragma unroll
    for (int ks = 0; ks < 4; ++ks) {
        const u16* g = Nbf + ((size_t)(m0 + w*16 + l15))*128 + ks*32 + lq*8;
        gload_lds16(g, smem + (size_t)((w*4 + ks)*64)*16);
    }
    __syncthreads();

    f32x4 acc[4];
    #pragma unroll
    for (int ms = 0; ms < 4; ++ms) acc[ms] = (f32x4){0,0,0,0};
    #pragma unroll
    for (int ms = 0; ms < 4; ++ms)
        #pragma unroll
        for (int ks = 0; ks < 4; ++ks) {
            bf16x8 a = *(const bf16x8*)(smem + (size_t)(((ms*4+ks)*64 + lane))*16);
            acc[ms] = __builtin_amdgcn_mfma_f32_16x16x32_bf16(a, bw[ks], acc[ms], 0,0,0);
        }

    int j = j0w + l15;
    if (j < D_HID) {
        float bo = bn[j];
        #pragma unroll
        for (int ms = 0; ms < 4; ++ms)
            #pragma unroll
            for (int i = 0; i < 4; ++i)
                outN[(size_t)(m0 + ms*16 + lq*4 + i)*D_HID + j] = acc[ms][i] + bo;
    }
}

extern "C" void kernel_launch(void* const* d_in, const int* in_sizes, int n_in,
                              void* d_out, int out_size, void* d_ws, size_t ws_size,
                              hipStream_t stream) {
    const float* nodes  = (const float*)d_in[0];
    const float* ctx    = (const float*)d_in[1];
    const int*   trip   = (const int*)d_in[2];
    const float* Wm     = (const float*)d_in[4];
    const float* bm     = (const float*)d_in[5];
    const float* Wihf   = (const float*)d_in[6];
    const float* bihf   = (const float*)d_in[7];
    const float* bhhf   = (const float*)d_in[8];
    const float* Wihb   = (const float*)d_in[9];
    const float* bihb   = (const float*)d_in[10];
    const float* bhhb   = (const float*)d_in[11];
    const float* Wout   = (const float*)d_in[12];
    const float* bout   = (const float*)d_in[13];
    const float* Wnode  = (const float*)d_in[14];
    const float* bnode  = (const float*)d_in[15];
    const float* gamma  = (const float*)d_in[16];
    const float* beta   = (const float*)d_in[17];
    float* out = (float*)d_out;

    char* ws = (char*)d_ws;
    u16*   W4bf   = (u16*)(ws);                       // 491,520 B
    u16*   Woutbf = (u16*)(ws + 491520);              // 466,944 B
    u16*   Wnbf   = (u16*)(ws + 958464);              //  81,920 B
    float* bc     = (float*)(ws + 1040384);           //   7,680 B
    float* bhhn   = (float*)(ws + 1048064);           //   2,560 B
    u16*   H      = (u16*)(ws + 1050624);             // 79,691,776 B  [65536][608]
    char*  hidbase = ws + 1050624 + 79691776ull;      // 80,742,400
    u16*   Hid    = (u16*)hidbase;                    // 39,321,600 B  [65536][300]
    u32*   Abf    = (u32*)hidbase;                    // overlay: 16,777,216 B (dead after k1)
    u32*   Nbf    = (u32*)(hidbase + 16777216ull);    // overlay:  8,388,608 B (dead after k5)
    float* alpha  = (float*)(ws + 120064000ull);      // 262,144 B  -> total 120,326,144 B

    hipMemsetAsync(alpha, 0, 65536*sizeof(float), stream);

    k0_prep<<<dim3(320,3,2), 128, 0, stream>>>(Wm,bm,Wihf,bihf,bhhf,Wihb,bihb,bhhb,W4bf,bc,bhhn);
    kW     <<<1072, 256, 0, stream>>>(Wout,Wnode,Woutbf,Wnbf);
    kA     <<<384,  256, 0, stream>>>(nodes,trip,Abf,Nbf,H);
    k1_gru <<<dim3(1024,10), 256, 0, stream>>>((const u16*)Abf,W4bf,bc,bhhn,H);
    k5_node<<<dim3(512,5),   256, 0, stream>>>((const u16*)Nbf,Wnbf,bnode,out + 38400);   // before k2 (overlay!)
    k2_out <<<dim3(1024,3),  256, 0, stream>>>(H,Woutbf,bout,Hid);
    k3_attn<<<dim3(8,128),   256, 0, stream>>>(ctx,Hid,alpha);
    k4_rep <<<128,           320, 0, stream>>>(alpha,Hid,gamma,beta,out);
    hipMemsetAsync(out + 38400 + 9830400, 0, 32768*sizeof(float), stream);
}

// Round 3
// 517.344 us; speedup vs baseline: 2.7473x; 1.4658x over previous
//
#include <hip/hip_runtime.h>
#include <math.h>

#define D_NODE 100
#define D_HID  300
static const int TSEQ = 512, LQn = 256, NNODE = 256;

typedef unsigned int u32;
typedef unsigned short u16;
typedef __attribute__((ext_vector_type(8))) short bf16x8;   // 8 bf16 = 4 VGPRs
typedef __attribute__((ext_vector_type(4))) float f32x4;

__device__ __forceinline__ float bflo(u32 u){ return __uint_as_float(u << 16); }
__device__ __forceinline__ float bfhi(u32 u){ return __uint_as_float(u & 0xffff0000u); }
__device__ __forceinline__ float bf2f(u16 v){ return __uint_as_float(((u32)v) << 16); }
__device__ __forceinline__ u16 f2bf(float f){
    u32 u = __float_as_uint(f);
    return (u16)((u + 0x7fffu + ((u >> 16) & 1u)) >> 16);
}
__device__ __forceinline__ u32 pack_bf(float lo, float hi){
    return ((u32)f2bf(lo)) | (((u32)f2bf(hi)) << 16);
}
__device__ __forceinline__ void gload_lds16(const void* g, void* l){
    __builtin_amdgcn_global_load_lds(
        (const __attribute__((address_space(1))) u32*)g,
        (__attribute__((address_space(3))) u32*)l, 16, 0, 0);
}

// ---------------- K0: fold W_mean into GRU weights -> W4bf bf16 [dir][gate][320 j][128 k] ----------------
__global__ __launch_bounds__(128)
void k0_prep(const float* __restrict__ Wm, const float* __restrict__ bm,
             const float* __restrict__ Wihf, const float* __restrict__ bihf, const float* __restrict__ bhhf,
             const float* __restrict__ Wihb, const float* __restrict__ bihb, const float* __restrict__ bhhb,
             u16* __restrict__ W4bf, float* __restrict__ bc, float* __restrict__ bhhn)
{
    int j = blockIdx.x, g = blockIdx.y, dir = blockIdx.z;
    int tid = threadIdx.x;
    u16* wout = W4bf + ((size_t)((dir*3+g)*320 + j))*128;
    if (j >= D_HID) {
        wout[tid] = 0;
        if (tid == 0) { bc[(dir*3+g)*320 + j] = 0.f; if (g==2) bhhn[dir*320+j] = 0.f; }
        return;
    }
    const float* Wih = dir ? Wihb : Wihf;
    const float* bih = dir ? bihb : bihf;
    const float* bhh = dir ? bhhb : bhhf;
    const float* wrow = Wih + (size_t)(g*D_HID + j)*D_HID;
    int k = tid;
    float s = 0.f;
    if (k < D_NODE)
        for (int q = 0; q < D_HID; ++q)
            s = fmaf(wrow[q], Wm[q*D_NODE + k], s);
    wout[k] = f2bf(k < D_NODE ? s : 0.f);

    __shared__ float red[128];
    float p = 0.f;
    for (int q = tid; q < D_HID; q += 128) p = fmaf(bm[q], wrow[q], p);
    red[tid] = p;
    __syncthreads();
    for (int off = 64; off > 0; off >>= 1) {
        if (tid < off) red[tid] += red[tid + off];
        __syncthreads();
    }
    if (tid == 0) {
        float base = bih[g*D_HID + j] + red[0];
        if (g < 2) base += bhh[g*D_HID + j];
        bc[(dir*3+g)*320 + j] = base;
        if (g == 2) bhhn[dir*320 + j] = bhh[2*D_HID + j];
    }
}

// ---------------- KW: convert Wout -> [384][608] bf16, Wnode -> [320][128] bf16 (zero-padded) ----------------
__global__ __launch_bounds__(256)
void kW(const float* __restrict__ Wout, const float* __restrict__ Wnode,
        u16* __restrict__ Woutbf, u16* __restrict__ Wnbf)
{
    int idx = blockIdx.x*256 + threadIdx.x;
    if (idx < 384*608) {
        int j = idx / 608, k = idx % 608;
        float v = (j < D_HID && k < 600) ? Wout[(size_t)j*600 + k] : 0.f;
        Woutbf[idx] = f2bf(v);
    } else {
        int i2 = idx - 384*608;
        if (i2 < 320*128) {
            int j = i2 >> 7, k = i2 & 127;
            float v = (j < D_HID && k < D_NODE) ? Wnode[(size_t)j*D_NODE + k] : 0.f;
            Wnbf[i2] = f2bf(v);
        }
    }
}

// ---------------- KA: gather+mean -> Abf bf16 [65536][128]; nodes -> Nbf bf16 [32768][128] ----------------
__global__ __launch_bounds__(256)
void kA(const float* __restrict__ nodes, const int* __restrict__ trip,
        u32* __restrict__ Abf, u32* __restrict__ Nbf)
{
    int gid = blockIdx.x*256 + threadIdx.x;
    if (gid < 65536) {
        int b = gid >> 9;
        int hidx = trip[(size_t)gid*3];
        int tidx = trip[(size_t)gid*3 + 2];
        const float4* nh = (const float4*)(nodes + ((size_t)b*NNODE + hidx)*D_NODE);
        const float4* nt = (const float4*)(nodes + ((size_t)b*NNODE + tidx)*D_NODE);
        u32* ar = Abf + (size_t)gid*64;
        #pragma unroll 5
        for (int i = 0; i < 25; ++i) {
            float4 a = nh[i], c = nt[i];
            ar[i*2]   = pack_bf(0.5f*(a.x+c.x), 0.5f*(a.y+c.y));
            ar[i*2+1] = pack_bf(0.5f*(a.z+c.z), 0.5f*(a.w+c.w));
        }
        #pragma unroll
        for (int i = 50; i < 64; ++i) ar[i] = 0;
    } else {
        int r = gid - 65536;
        if (r < 32768) {
            const float4* nr = (const float4*)(nodes + (size_t)r*D_NODE);
            u32* ar = Nbf + (size_t)r*64;
            #pragma unroll 5
            for (int i = 0; i < 25; ++i) {
                float4 a = nr[i];
                ar[i*2]   = pack_bf(a.x, a.y);
                ar[i*2+1] = pack_bf(a.z, a.w);
            }
            #pragma unroll
            for (int i = 50; i < 64; ++i) ar[i] = 0;
        }
    }
}

// ---------------- KC: ctx -> bf16 padded [32768][320] (runs after k2; lives in dead H region) ----------------
__global__ __launch_bounds__(256)
void kC(const float* __restrict__ ctx, u32* __restrict__ Cbf)
{
    int idx = blockIdx.x*256 + threadIdx.x;     // over 32768*160 u32
    int r = idx / 160, cp = idx % 160;
    int col = cp*2;
    u32 v = 0;
    if (col < D_HID) {
        float2 f = *(const float2*)(ctx + (size_t)r*D_HID + col);
        v = pack_bf(f.x, f.y);
    }
    Cbf[(size_t)r*160 + cp] = v;
}

// ---------------- K1: MFMA GEMM + GRU epilogue -> H[M][608] bf16 ----------------
__global__ __launch_bounds__(256)
void k1_gru(const u16* __restrict__ Abf, const u16* __restrict__ W4bf,
            const float* __restrict__ bc, const float* __restrict__ bhhn,
            u16* __restrict__ H)
{
    __shared__ char smem[16384];
    int tid = threadIdx.x;
    int lane = tid & 63, w = tid >> 6;
    int l15 = lane & 15, lq = lane >> 4;
    int m0 = blockIdx.x * 64;
    int dir = blockIdx.y / 5;
    int jg = blockIdx.y % 5;
    int j0w = jg*64 + w*16;

    bf16x8 bfr[3][4];
    const u16* Wb = W4bf + (size_t)dir*3*320*128;
    #pragma unroll
    for (int g = 0; g < 3; ++g)
        #pragma unroll
        for (int ks = 0; ks < 4; ++ks)
            bfr[g][ks] = *(const bf16x8*)(Wb + ((size_t)(g*320 + j0w + l15))*128 + ks*32 + lq*8);

    #pragma unroll
    for (int ks = 0; ks < 4; ++ks) {
        const u16* g = Abf + ((size_t)(m0 + w*16 + l15))*128 + ks*32 + lq*8;
        gload_lds16(g, smem + (size_t)((w*4 + ks)*64)*16);
    }
    __syncthreads();

    f32x4 acc[4][3];
    #pragma unroll
    for (int ms = 0; ms < 4; ++ms)
        #pragma unroll
        for (int g = 0; g < 3; ++g)
            acc[ms][g] = (f32x4){0.f,0.f,0.f,0.f};

    #pragma unroll
    for (int ms = 0; ms < 4; ++ms)
        #pragma unroll
        for (int ks = 0; ks < 4; ++ks) {
            bf16x8 a = *(const bf16x8*)(smem + (size_t)(((ms*4+ks)*64 + lane))*16);
            acc[ms][0] = __builtin_amdgcn_mfma_f32_16x16x32_bf16(a, bfr[0][ks], acc[ms][0], 0,0,0);
            acc[ms][1] = __builtin_amdgcn_mfma_f32_16x16x32_bf16(a, bfr[1][ks], acc[ms][1], 0,0,0);
            acc[ms][2] = __builtin_amdgcn_mfma_f32_16x16x32_bf16(a, bfr[2][ks], acc[ms][2], 0,0,0);
        }

    int j = j0w + l15;
    float bcr = bc[(dir*3+0)*320 + j];
    float bcz = bc[(dir*3+1)*320 + j];
    float bcn = bc[(dir*3+2)*320 + j];
    float bn2 = bhhn[dir*320 + j];
    bool ok = (j < D_HID);
    #pragma unroll
    for (int ms = 0; ms < 4; ++ms)
        #pragma unroll
        for (int i = 0; i < 4; ++i) {
            float r = 1.f/(1.f + __expf(-(acc[ms][0][i] + bcr)));
            float z = 1.f/(1.f + __expf(-(acc[ms][1][i] + bcz)));
            float n = tanhf(acc[ms][2][i] + bcn + r*bn2);
            float h = (1.f - z)*n;
            if (ok) H[(size_t)(m0 + ms*16 + lq*4 + i)*608 + dir*D_HID + j] = f2bf(h);
        }
}

// ---------------- K2: Hid = tanh(H @ Wout^T + bout) via MFMA -> bf16 [M][320] (zero-padded) ----------------
__global__ __launch_bounds__(256, 2)
void k2_out(const u16* __restrict__ H, const u16* __restrict__ Woutbf,
            const float* __restrict__ bout, u16* __restrict__ Hid)
{
    __shared__ char smem[40960];
    int tid = threadIdx.x;
    int lane = tid & 63, w = tid >> 6;
    int l15 = lane & 15, lq = lane >> 4;
    int m0 = blockIdx.x * 64;
    int j0 = blockIdx.y * 128;
    int jA = j0 + w*16, jB = j0 + 64 + w*16;

    bf16x8 bA[19], bB[19];
    #pragma unroll
    for (int ks = 0; ks < 19; ++ks) {
        bA[ks] = *(const bf16x8*)(Woutbf + ((size_t)(jA + l15))*608 + ks*32 + lq*8);
        bB[ks] = *(const bf16x8*)(Woutbf + ((size_t)(jB + l15))*608 + ks*32 + lq*8);
    }
    f32x4 acc[4][2];
    #pragma unroll
    for (int ms = 0; ms < 4; ++ms) { acc[ms][0] = (f32x4){0,0,0,0}; acc[ms][1] = (f32x4){0,0,0,0}; }

    #pragma unroll
    for (int c = 0; c < 2; ++c) {
        const int kb = c ? 10 : 0;
        const int nks = c ? 9 : 10;
        #pragma unroll
        for (int kk = 0; kk < 10; ++kk)
            if (kk < nks) {
                const u16* g = H + ((size_t)(m0 + w*16 + l15))*608 + (kb+kk)*32 + lq*8;
                gload_lds16(g, smem + (size_t)((w*10 + kk)*64)*16);
            }
        __syncthreads();
        #pragma unroll
        for (int ms = 0; ms < 4; ++ms)
            #pragma unroll
            for (int kk = 0; kk < 10; ++kk)
                if (kk < nks) {
                    bf16x8 a = *(const bf16x8*)(smem + (size_t)(((ms*10+kk)*64 + lane))*16);
                    acc[ms][0] = __builtin_amdgcn_mfma_f32_16x16x32_bf16(a, bA[kb+kk], acc[ms][0], 0,0,0);
                    acc[ms][1] = __builtin_amdgcn_mfma_f32_16x16x32_bf16(a, bB[kb+kk], acc[ms][1], 0,0,0);
                }
        __syncthreads();
    }

    #pragma unroll
    for (int jj = 0; jj < 2; ++jj) {
        int j = (jj ? jB : jA) + l15;
        if (j < 320) {
            bool real = (j < D_HID);
            float bo = real ? bout[j] : 0.f;
            #pragma unroll
            for (int ms = 0; ms < 4; ++ms)
                #pragma unroll
                for (int i = 0; i < 4; ++i) {
                    u16 v = real ? f2bf(tanhf(acc[ms][jj][i] + bo)) : (u16)0;
                    Hid[(size_t)(m0 + ms*16 + lq*4 + i)*320 + j] = v;
                }
        }
    }
}

// ---------------- K3a: Sc[b][l][t] = ctx[b] @ Hid[b]^T via MFMA -> bf16 ----------------
// grid (8, 128): x = mt(4) | nt2(2); block: M=64 l, N=256 t, K=320
__global__ __launch_bounds__(256)
void k3a_score(const u16* __restrict__ Cbf, const u16* __restrict__ Hid,
               u16* __restrict__ Sc)
{
    __shared__ char smem[20480];   // A: 4x64x16 = 4096 B; B: 16x64x16 = 16384 B
    int tid = threadIdx.x;
    int lane = tid & 63, w = tid >> 6;
    int l15 = lane & 15, lq = lane >> 4;
    int b = blockIdx.y;
    int mt = blockIdx.x & 3;
    int nt2 = blockIdx.x >> 2;
    int m0 = mt*64;
    int t0 = nt2*256;
    const u16* Ab = Cbf + ((size_t)b*LQn + m0)*320;
    const u16* Bb = Hid + ((size_t)b*TSEQ + t0)*320;

    f32x4 acc[4][4];
    #pragma unroll
    for (int ms = 0; ms < 4; ++ms)
        #pragma unroll
        for (int nt = 0; nt < 4; ++nt)
            acc[ms][nt] = (f32x4){0,0,0,0};

    for (int ks = 0; ks < 10; ++ks) {
        gload_lds16(Ab + ((size_t)(w*16 + l15))*320 + ks*32 + lq*8,
                    smem + (size_t)(w*64)*16);
        #pragma unroll
        for (int i = 0; i < 4; ++i) {
            int nt = w*4 + i;
            gload_lds16(Bb + ((size_t)(nt*16 + l15))*320 + ks*32 + lq*8,
                        smem + 4096 + (size_t)(nt*64)*16);
        }
        __syncthreads();
        bf16x8 afr[4];
        #pragma unroll
        for (int ms = 0; ms < 4; ++ms)
            afr[ms] = *(const bf16x8*)(smem + (size_t)((ms*64 + lane))*16);
        #pragma unroll
        for (int i = 0; i < 4; ++i) {
            bf16x8 bfr = *(const bf16x8*)(smem + 4096 + (size_t)(((w*4+i)*64 + lane))*16);
            #pragma unroll
            for (int ms = 0; ms < 4; ++ms)
                acc[ms][i] = __builtin_amdgcn_mfma_f32_16x16x32_bf16(afr[ms], bfr, acc[ms][i], 0,0,0);
        }
        __syncthreads();
    }
    #pragma unroll
    for (int ms = 0; ms < 4; ++ms)
        #pragma unroll
        for (int i = 0; i < 4; ++i) {
            int t = t0 + (w*4+i)*16 + l15;
            #pragma unroll
            for (int r = 0; r < 4; ++r) {
                int l = m0 + ms*16 + lq*4 + r;
                Sc[((size_t)b*LQn + l)*TSEQ + t] = f2bf(acc[ms][i][r]);
            }
        }
}

// ---------------- K3b: softmax over t per (b,l), alpha[b][t] = sum_l p ----------------
__global__ __launch_bounds__(256)
void k3b_softmax(const u16* __restrict__ Sc, float* __restrict__ alpha)
{
    __shared__ float mrow[256], sinv[256];
    int tid = threadIdx.x, b = blockIdx.x;
    int lane = tid & 63, w = tid >> 6;
    const u16* Sb = Sc + (size_t)b*LQn*TSEQ;

    for (int i = 0; i < 64; ++i) {
        int l = i*4 + w;
        bf16x8 v = *(const bf16x8*)(Sb + (size_t)l*TSEQ + lane*8);
        float f[8];
        #pragma unroll
        for (int j = 0; j < 8; ++j) f[j] = bf2f((u16)v[j]);
        float m = f[0];
        #pragma unroll
        for (int j = 1; j < 8; ++j) m = fmaxf(m, f[j]);
        #pragma unroll
        for (int off = 32; off > 0; off >>= 1) m = fmaxf(m, __shfl_xor(m, off));
        float s = 0.f;
        #pragma unroll
        for (int j = 0; j < 8; ++j) s += __expf(f[j] - m);
        #pragma unroll
        for (int off = 32; off > 0; off >>= 1) s += __shfl_xor(s, off);
        if (lane == 0) { mrow[l] = m; sinv[l] = 1.f/s; }
    }
    __syncthreads();
    int t0 = tid*2;
    float a0 = 0.f, a1 = 0.f;
    for (int l = 0; l < 256; ++l) {
        u32 u = *(const u32*)(Sb + (size_t)l*TSEQ + t0);
        float m = mrow[l], si = sinv[l];
        a0 += __expf(bflo(u) - m)*si;
        a1 += __expf(bfhi(u) - m)*si;
    }
    alpha[(size_t)b*TSEQ + t0]     = a0;
    alpha[(size_t)b*TSEQ + t0 + 1] = a1;
}

// ---------------- K4: rep = alpha @ Hid ; layernorm -> path_feature ----------------
__global__ __launch_bounds__(320)
void k4_rep(const float* __restrict__ alpha, const u16* __restrict__ Hid,
            const float* __restrict__ gamma, const float* __restrict__ beta,
            float* __restrict__ outP)
{
    __shared__ float al[512];
    __shared__ float rs[5], rss[5];
    int tid = threadIdx.x, b = blockIdx.x;
    for (int i = tid; i < 512; i += 320) al[i] = alpha[(size_t)b*TSEQ + i];
    __syncthreads();
    float acc = 0.f;
    if (tid < D_HID) {
        const u16* hp = Hid + (size_t)b*TSEQ*320 + tid;
        #pragma unroll 8
        for (int t = 0; t < TSEQ; ++t)
            acc = fmaf(al[t], bf2f(hp[(size_t)t*320]), acc);
    }
    float v = (tid < D_HID) ? acc : 0.f;
    float s = v, q = v*v;
    #pragma unroll
    for (int off = 32; off > 0; off >>= 1) { s += __shfl_xor(s, off, 64); q += __shfl_xor(q, off, 64); }
    if ((tid & 63) == 0) { rs[tid >> 6] = s; rss[tid >> 6] = q; }
    __syncthreads();
    float S = rs[0]+rs[1]+rs[2]+rs[3]+rs[4];
    float Q = rss[0]+rss[1]+rss[2]+rss[3]+rss[4];
    float mu = S * (1.f/300.f);
    float var = Q * (1.f/300.f) - mu*mu;
    if (tid < D_HID)
        outP[(size_t)b*D_HID + tid] = (acc - mu) * rsqrtf(var + 1e-5f) * gamma[tid] + beta[tid];
}

// ---------------- K5: node_feature = nodes @ Wnode^T + bnode via MFMA (fp32 out) ----------------
__global__ __launch_bounds__(256)
void k5_node(const u16* __restrict__ Nbf, const u16* __restrict__ Wnbf,
             const float* __restrict__ bn, float* __restrict__ outN)
{
    __shared__ char smem[16384];
    int tid = threadIdx.x;
    int lane = tid & 63, w = tid >> 6;
    int l15 = lane & 15, lq = lane >> 4;
    int m0 = blockIdx.x * 64;
    int j0w = blockIdx.y*64 + w*16;

    bf16x8 bw[4];
    #pragma unroll
    for (int ks = 0; ks < 4; ++ks)
        bw[ks] = *(const bf16x8*)(Wnbf + ((size_t)(j0w + l15))*128 + ks*32 + lq*8);

    #pragma unroll
    for (int ks = 0; ks < 4; ++ks) {
        const u16* g = Nbf + ((size_t)(m0 + w*16 + l15))*128 + ks*32 + lq*8;
        gload_lds16(g, smem + (size_t)((w*4 + ks)*64)*16);
    }
    __syncthreads();

    f32x4 acc[4];
    #pragma unroll
    for (int ms = 0; ms < 4; ++ms) acc[ms] = (f32x4){0,0,0,0};
    #pragma unroll
    for (int ms = 0; ms < 4; ++ms)
        #pragma unroll
        for (int ks = 0; ks < 4; ++ks) {
            bf16x8 a = *(const bf16x8*)(smem + (size_t)(((ms*4+ks)*64 + lane))*16);
            acc[ms] = __builtin_amdgcn_mfma_f32_16x16x32_bf16(a, bw[ks], acc[ms], 0,0,0);
        }

    int j = j0w + l15;
    if (j < D_HID) {
        float bo = bn[j];
        #pragma unroll
        for (int ms = 0; ms < 4; ++ms)
            #pragma unroll
            for (int i = 0; i < 4; ++i)
                outN[(size_t)(m0 + ms*16 + lq*4 + i)*D_HID + j] = acc[ms][i] + bo;
    }
}

extern "C" void kernel_launch(void* const* d_in, const int* in_sizes, int n_in,
                              void* d_out, int out_size, void* d_ws, size_t ws_size,
                              hipStream_t stream) {
    const float* nodes  = (const float*)d_in[0];
    const float* ctx    = (const float*)d_in[1];
    const int*   trip   = (const int*)d_in[2];
    const float* Wm     = (const float*)d_in[4];
    const float* bm     = (const float*)d_in[5];
    const float* Wihf   = (const float*)d_in[6];
    const float* bihf   = (const float*)d_in[7];
    const float* bhhf   = (const float*)d_in[8];
    const float* Wihb   = (const float*)d_in[9];
    const float* bihb   = (const float*)d_in[10];
    const float* bhhb   = (const float*)d_in[11];
    const float* Wout   = (const float*)d_in[12];
    const float* bout   = (const float*)d_in[13];
    const float* Wnode  = (const float*)d_in[14];
    const float* bnode  = (const float*)d_in[15];
    const float* gamma  = (const float*)d_in[16];
    const float* beta   = (const float*)d_in[17];
    float* out = (float*)d_out;

    char* ws = (char*)d_ws;
    u16*   W4bf   = (u16*)(ws);                         // 491,520 B
    u16*   Woutbf = (u16*)(ws + 491520);                // 466,944 B
    u16*   Wnbf   = (u16*)(ws + 958464);                //  81,920 B
    float* bc     = (float*)(ws + 1040384);             //   7,680 B
    float* bhhn   = (float*)(ws + 1048064);             //   2,560 B
    char*  Hbase  = ws + 1050624;
    u16*   H      = (u16*)Hbase;                        // 79,691,776 B  [65536][608]
    u16*   Sc     = (u16*)Hbase;                        // overlay (after k2): 33,554,432 B
    u32*   Cbf    = (u32*)(Hbase + 33554432ull);        // overlay (after k2): 20,971,520 B
    char*  hidbase = Hbase + 79691776ull;               // 80,742,400
    u16*   Hid    = (u16*)hidbase;                      // 41,943,040 B  [65536][320]
    u32*   Abf    = (u32*)hidbase;                      // overlay: 16,777,216 B (dead before k2)
    u32*   Nbf    = (u32*)(hidbase + 16777216ull);      // overlay:  8,388,608 B (dead before k2)
    float* alpha  = (float*)(ws + 122685440ull);        // 262,144 B -> total 122,947,584 B

    k0_prep<<<dim3(320,3,2), 128, 0, stream>>>(Wm,bm,Wihf,bihf,bhhf,Wihb,bihb,bhhb,W4bf,bc,bhhn);
    kW     <<<1072, 256, 0, stream>>>(Wout,Wnode,Woutbf,Wnbf);
    kA     <<<384,  256, 0, stream>>>(nodes,trip,Abf,Nbf);
    k1_gru <<<dim3(1024,10), 256, 0, stream>>>((const u16*)Abf,W4bf,bc,bhhn,H);
    k5_node<<<dim3(512,5),   256, 0, stream>>>((const u16*)Nbf,Wnbf,bnode,out + 38400);   // before k2 (overlay!)
    k2_out <<<dim3(1024,3),  256, 0, stream>>>(H,Woutbf,bout,Hid);
    kC     <<<20480, 256, 0, stream>>>(ctx, Cbf);                                          // after k2 (overlay!)
    k3a_score<<<dim3(8,128), 256, 0, stream>>>((const u16*)Cbf, Hid, Sc);
    k3b_softmax<<<128, 256, 0, stream>>>(Sc, alpha);
    k4_rep <<<128,           320, 0, stream>>>(alpha,Hid,gamma,beta,out);
    hipMemsetAsync(out + 38400 + 9830400, 0, 32768*sizeof(float), stream);
}

// Round 4
// 442.124 us; speedup vs baseline: 3.2148x; 1.1701x over previous
//
#include <hip/hip_runtime.h>
#include <math.h>

#define D_NODE 100
#define D_HID  300
static const int TSEQ = 512, LQn = 256, NNODE = 256;

typedef unsigned int u32;
typedef unsigned short u16;
typedef __attribute__((ext_vector_type(8))) short bf16x8;   // 8 bf16 = 4 VGPRs
typedef __attribute__((ext_vector_type(4))) float f32x4;

__device__ __forceinline__ float bflo(u32 u){ return __uint_as_float(u << 16); }
__device__ __forceinline__ float bfhi(u32 u){ return __uint_as_float(u & 0xffff0000u); }
__device__ __forceinline__ float bf2f(u16 v){ return __uint_as_float(((u32)v) << 16); }
__device__ __forceinline__ u16 f2bf(float f){
    u32 u = __float_as_uint(f);
    return (u16)((u + 0x7fffu + ((u >> 16) & 1u)) >> 16);
}
__device__ __forceinline__ u32 pack_bf(float lo, float hi){
    return ((u32)f2bf(lo)) | (((u32)f2bf(hi)) << 16);
}
__device__ __forceinline__ void gload_lds16(const void* g, void* l){
    __builtin_amdgcn_global_load_lds(
        (const __attribute__((address_space(1))) u32*)g,
        (__attribute__((address_space(3))) u32*)l, 16, 0, 0);
}
// fast sigmoid / tanh on v_exp_f32 + v_rcp_f32 (saturate correctly at +/-inf)
__device__ __forceinline__ float fsig(float x){
    return __builtin_amdgcn_rcpf(1.f + __expf(-x));
}
__device__ __forceinline__ float ftanh(float x){
    return 1.f - 2.f*__builtin_amdgcn_rcpf(1.f + __expf(2.f*x));
}

// ---------------- K0: fold W_mean into GRU weights -> W4bf bf16 [dir][gate][320 j][128 k] ----------------
__global__ __launch_bounds__(128)
void k0_prep(const float* __restrict__ Wm, const float* __restrict__ bm,
             const float* __restrict__ Wihf, const float* __restrict__ bihf, const float* __restrict__ bhhf,
             const float* __restrict__ Wihb, const float* __restrict__ bihb, const float* __restrict__ bhhb,
             u16* __restrict__ W4bf, float* __restrict__ bc, float* __restrict__ bhhn)
{
    int j = blockIdx.x, g = blockIdx.y, dir = blockIdx.z;
    int tid = threadIdx.x;
    u16* wout = W4bf + ((size_t)((dir*3+g)*320 + j))*128;
    if (j >= D_HID) {
        wout[tid] = 0;
        if (tid == 0) { bc[(dir*3+g)*320 + j] = 0.f; if (g==2) bhhn[dir*320+j] = 0.f; }
        return;
    }
    const float* Wih = dir ? Wihb : Wihf;
    const float* bih = dir ? bihb : bihf;
    const float* bhh = dir ? bhhb : bhhf;
    const float* wrow = Wih + (size_t)(g*D_HID + j)*D_HID;
    int k = tid;
    float s = 0.f;
    if (k < D_NODE)
        for (int q = 0; q < D_HID; ++q)
            s = fmaf(wrow[q], Wm[q*D_NODE + k], s);
    wout[k] = f2bf(k < D_NODE ? s : 0.f);

    __shared__ float red[128];
    float p = 0.f;
    for (int q = tid; q < D_HID; q += 128) p = fmaf(bm[q], wrow[q], p);
    red[tid] = p;
    __syncthreads();
    for (int off = 64; off > 0; off >>= 1) {
        if (tid < off) red[tid] += red[tid + off];
        __syncthreads();
    }
    if (tid == 0) {
        float base = bih[g*D_HID + j] + red[0];
        if (g < 2) base += bhh[g*D_HID + j];
        bc[(dir*3+g)*320 + j] = base;
        if (g == 2) bhhn[dir*320 + j] = bhh[2*D_HID + j];
    }
}

// ---------------- KW: convert Wout -> [384][608] bf16, Wnode -> [320][128] bf16 (zero-padded) ----------------
__global__ __launch_bounds__(256)
void kW(const float* __restrict__ Wout, const float* __restrict__ Wnode,
        u16* __restrict__ Woutbf, u16* __restrict__ Wnbf)
{
    int idx = blockIdx.x*256 + threadIdx.x;
    if (idx < 384*608) {
        int j = idx / 608, k = idx % 608;
        float v = (j < D_HID && k < 600) ? Wout[(size_t)j*600 + k] : 0.f;
        Woutbf[idx] = f2bf(v);
    } else {
        int i2 = idx - 384*608;
        if (i2 < 320*128) {
            int j = i2 >> 7, k = i2 & 127;
            float v = (j < D_HID && k < D_NODE) ? Wnode[(size_t)j*D_NODE + k] : 0.f;
            Wnbf[i2] = f2bf(v);
        }
    }
}

// ---------------- KA: gather+mean -> Abf bf16 [65536][128]; nodes -> Nbf bf16 [32768][128] ----------------
__global__ __launch_bounds__(256)
void kA(const float* __restrict__ nodes, const int* __restrict__ trip,
        u32* __restrict__ Abf, u32* __restrict__ Nbf)
{
    int gid = blockIdx.x*256 + threadIdx.x;
    if (gid < 65536) {
        int b = gid >> 9;
        int hidx = trip[(size_t)gid*3];
        int tidx = trip[(size_t)gid*3 + 2];
        const float4* nh = (const float4*)(nodes + ((size_t)b*NNODE + hidx)*D_NODE);
        const float4* nt = (const float4*)(nodes + ((size_t)b*NNODE + tidx)*D_NODE);
        u32* ar = Abf + (size_t)gid*64;
        #pragma unroll 5
        for (int i = 0; i < 25; ++i) {
            float4 a = nh[i], c = nt[i];
            ar[i*2]   = pack_bf(0.5f*(a.x+c.x), 0.5f*(a.y+c.y));
            ar[i*2+1] = pack_bf(0.5f*(a.z+c.z), 0.5f*(a.w+c.w));
        }
        #pragma unroll
        for (int i = 50; i < 64; ++i) ar[i] = 0;
    } else {
        int r = gid - 65536;
        if (r < 32768) {
            const float4* nr = (const float4*)(nodes + (size_t)r*D_NODE);
            u32* ar = Nbf + (size_t)r*64;
            #pragma unroll 5
            for (int i = 0; i < 25; ++i) {
                float4 a = nr[i];
                ar[i*2]   = pack_bf(a.x, a.y);
                ar[i*2+1] = pack_bf(a.z, a.w);
            }
            #pragma unroll
            for (int i = 50; i < 64; ++i) ar[i] = 0;
        }
    }
}

// ---------------- KC: ctx -> bf16 padded [32768][320] (runs after k2; lives in dead H region) ----------------
__global__ __launch_bounds__(256)
void kC(const float* __restrict__ ctx, u32* __restrict__ Cbf)
{
    int idx = blockIdx.x*256 + threadIdx.x;     // over 32768*160 u32
    int r = idx / 160, cp = idx % 160;
    int col = cp*2;
    u32 v = 0;
    if (col < D_HID) {
        float2 f = *(const float2*)(ctx + (size_t)r*D_HID + col);
        v = pack_bf(f.x, f.y);
    }
    Cbf[(size_t)r*160 + cp] = v;
}

// ---------------- K1: MFMA GEMM + GRU epilogue -> H[M][608] bf16 ----------------
__global__ __launch_bounds__(256)
void k1_gru(const u16* __restrict__ Abf, const u16* __restrict__ W4bf,
            const float* __restrict__ bc, const float* __restrict__ bhhn,
            u16* __restrict__ H)
{
    __shared__ char smem[16384];
    int tid = threadIdx.x;
    int lane = tid & 63, w = tid >> 6;
    int l15 = lane & 15, lq = lane >> 4;
    int m0 = blockIdx.x * 64;
    int dir = blockIdx.y / 5;
    int jg = blockIdx.y % 5;
    int j0w = jg*64 + w*16;

    bf16x8 bfr[3][4];
    const u16* Wb = W4bf + (size_t)dir*3*320*128;
    #pragma unroll
    for (int g = 0; g < 3; ++g)
        #pragma unroll
        for (int ks = 0; ks < 4; ++ks)
            bfr[g][ks] = *(const bf16x8*)(Wb + ((size_t)(g*320 + j0w + l15))*128 + ks*32 + lq*8);

    #pragma unroll
    for (int ks = 0; ks < 4; ++ks) {
        const u16* g = Abf + ((size_t)(m0 + w*16 + l15))*128 + ks*32 + lq*8;
        gload_lds16(g, smem + (size_t)((w*4 + ks)*64)*16);
    }
    __syncthreads();

    f32x4 acc[4][3];
    #pragma unroll
    for (int ms = 0; ms < 4; ++ms)
        #pragma unroll
        for (int g = 0; g < 3; ++g)
            acc[ms][g] = (f32x4){0.f,0.f,0.f,0.f};

    #pragma unroll
    for (int ms = 0; ms < 4; ++ms)
        #pragma unroll
        for (int ks = 0; ks < 4; ++ks) {
            bf16x8 a = *(const bf16x8*)(smem + (size_t)(((ms*4+ks)*64 + lane))*16);
            acc[ms][0] = __builtin_amdgcn_mfma_f32_16x16x32_bf16(a, bfr[0][ks], acc[ms][0], 0,0,0);
            acc[ms][1] = __builtin_amdgcn_mfma_f32_16x16x32_bf16(a, bfr[1][ks], acc[ms][1], 0,0,0);
            acc[ms][2] = __builtin_amdgcn_mfma_f32_16x16x32_bf16(a, bfr[2][ks], acc[ms][2], 0,0,0);
        }

    int j = j0w + l15;
    float bcr = bc[(dir*3+0)*320 + j];
    float bcz = bc[(dir*3+1)*320 + j];
    float bcn = bc[(dir*3+2)*320 + j];
    float bn2 = bhhn[dir*320 + j];
    bool ok = (j < D_HID);
    #pragma unroll
    for (int ms = 0; ms < 4; ++ms)
        #pragma unroll
        for (int i = 0; i < 4; ++i) {
            float r = fsig(acc[ms][0][i] + bcr);
            float z = fsig(acc[ms][1][i] + bcz);
            float n = ftanh(acc[ms][2][i] + bcn + r*bn2);
            float h = (1.f - z)*n;
            if (ok) H[(size_t)(m0 + ms*16 + lq*4 + i)*608 + dir*D_HID + j] = f2bf(h);
        }
}

// ---------------- K2: Hid = tanh(H @ Wout^T + bout) via MFMA -> bf16 [M][320] (zero-padded) ----------------
__global__ __launch_bounds__(256, 2)
void k2_out(const u16* __restrict__ H, const u16* __restrict__ Woutbf,
            const float* __restrict__ bout, u16* __restrict__ Hid)
{
    __shared__ char smem[40960];
    int tid = threadIdx.x;
    int lane = tid & 63, w = tid >> 6;
    int l15 = lane & 15, lq = lane >> 4;
    int m0 = blockIdx.x * 64;
    int j0 = blockIdx.y * 128;
    int jA = j0 + w*16, jB = j0 + 64 + w*16;

    bf16x8 bA[19], bB[19];
    #pragma unroll
    for (int ks = 0; ks < 19; ++ks) {
        bA[ks] = *(const bf16x8*)(Woutbf + ((size_t)(jA + l15))*608 + ks*32 + lq*8);
        bB[ks] = *(const bf16x8*)(Woutbf + ((size_t)(jB + l15))*608 + ks*32 + lq*8);
    }
    f32x4 acc[4][2];
    #pragma unroll
    for (int ms = 0; ms < 4; ++ms) { acc[ms][0] = (f32x4){0,0,0,0}; acc[ms][1] = (f32x4){0,0,0,0}; }

    #pragma unroll
    for (int c = 0; c < 2; ++c) {
        const int kb = c ? 10 : 0;
        const int nks = c ? 9 : 10;
        #pragma unroll
        for (int kk = 0; kk < 10; ++kk)
            if (kk < nks) {
                const u16* g = H + ((size_t)(m0 + w*16 + l15))*608 + (kb+kk)*32 + lq*8;
                gload_lds16(g, smem + (size_t)((w*10 + kk)*64)*16);
            }
        __syncthreads();
        #pragma unroll
        for (int ms = 0; ms < 4; ++ms)
            #pragma unroll
            for (int kk = 0; kk < 10; ++kk)
                if (kk < nks) {
                    bf16x8 a = *(const bf16x8*)(smem + (size_t)(((ms*10+kk)*64 + lane))*16);
                    acc[ms][0] = __builtin_amdgcn_mfma_f32_16x16x32_bf16(a, bA[kb+kk], acc[ms][0], 0,0,0);
                    acc[ms][1] = __builtin_amdgcn_mfma_f32_16x16x32_bf16(a, bB[kb+kk], acc[ms][1], 0,0,0);
                }
        __syncthreads();
    }

    #pragma unroll
    for (int jj = 0; jj < 2; ++jj) {
        int j = (jj ? jB : jA) + l15;
        if (j < 320) {
            bool real = (j < D_HID);
            float bo = real ? bout[j] : 0.f;
            #pragma unroll
            for (int ms = 0; ms < 4; ++ms)
                #pragma unroll
                for (int i = 0; i < 4; ++i) {
                    u16 v = real ? f2bf(ftanh(acc[ms][jj][i] + bo)) : (u16)0;
                    Hid[(size_t)(m0 + ms*16 + lq*4 + i)*320 + j] = v;
                }
        }
    }
}

// ---------------- K3: fused scores + softmax + partial-alpha ----------------
// grid (4, 128): block = 64 queries (m) x all 512 t, K=320. Scores live in VGPRs.
__global__ __launch_bounds__(256, 2)
void k3_attn(const u16* __restrict__ Cbf, const u16* __restrict__ Hid,
             float* __restrict__ alphap)
{
    __shared__ char smemA[4096];       // 4 m-groups x 64 x 16 B
    __shared__ char smemB[32768];      // 32 t-groups x 64 x 16 B
    __shared__ float rmax[64*4], rsum[64*4];
    int tid = threadIdx.x;
    int lane = tid & 63, w = tid >> 6;
    int l15 = lane & 15, lq = lane >> 4;
    int b = blockIdx.y;
    int mblk = blockIdx.x;
    const u16* Ab = Cbf + ((size_t)b*LQn + mblk*64)*320;
    const u16* Bb = Hid + ((size_t)b*TSEQ)*320;

    f32x4 acc[4][8];   // [m-group][t-group(of wave)] ; t = w*128 + g*16 + l15, row = ms*16+lq*4+i
    #pragma unroll
    for (int ms = 0; ms < 4; ++ms)
        #pragma unroll
        for (int g = 0; g < 8; ++g)
            acc[ms][g] = (f32x4){0,0,0,0};

    for (int ks = 0; ks < 10; ++ks) {
        gload_lds16(Ab + ((size_t)(w*16 + l15))*320 + ks*32 + lq*8,
                    smemA + (size_t)(w*64)*16);
        #pragma unroll
        for (int i = 0; i < 8; ++i) {
            int nt = w*8 + i;
            gload_lds16(Bb + ((size_t)(nt*16 + l15))*320 + ks*32 + lq*8,
                        smemB + (size_t)(nt*64)*16);
        }
        __syncthreads();
        bf16x8 afr[4];
        #pragma unroll
        for (int ms = 0; ms < 4; ++ms)
            afr[ms] = *(const bf16x8*)(smemA + (size_t)((ms*64 + lane))*16);
        #pragma unroll
        for (int i = 0; i < 8; ++i) {
            bf16x8 bfr = *(const bf16x8*)(smemB + (size_t)(((w*8+i)*64 + lane))*16);
            #pragma unroll
            for (int ms = 0; ms < 4; ++ms)
                acc[ms][i] = __builtin_amdgcn_mfma_f32_16x16x32_bf16(afr[ms], bfr, acc[ms][i], 0,0,0);
        }
        __syncthreads();
    }

    // ---- row max (cross-wave via LDS) ----
    #pragma unroll
    for (int ms = 0; ms < 4; ++ms)
        #pragma unroll
        for (int i = 0; i < 4; ++i) {
            float m = acc[ms][0][i];
            #pragma unroll
            for (int g = 1; g < 8; ++g) m = fmaxf(m, acc[ms][g][i]);
            m = fmaxf(m, __shfl_xor(m, 1));
            m = fmaxf(m, __shfl_xor(m, 2));
            m = fmaxf(m, __shfl_xor(m, 4));
            m = fmaxf(m, __shfl_xor(m, 8));
            if (l15 == 0) rmax[(ms*16 + lq*4 + i)*4 + w] = m;
        }
    __syncthreads();
    float mfin[4][4];
    #pragma unroll
    for (int ms = 0; ms < 4; ++ms)
        #pragma unroll
        for (int i = 0; i < 4; ++i) {
            float4 mv = *(const float4*)&rmax[(ms*16 + lq*4 + i)*4];
            mfin[ms][i] = fmaxf(fmaxf(mv.x, mv.y), fmaxf(mv.z, mv.w));
        }
    // ---- exp in place + row sum ----
    #pragma unroll
    for (int ms = 0; ms < 4; ++ms)
        #pragma unroll
        for (int i = 0; i < 4; ++i) {
            float s = 0.f;
            #pragma unroll
            for (int g = 0; g < 8; ++g) {
                float e = __expf(acc[ms][g][i] - mfin[ms][i]);
                acc[ms][g][i] = e;
                s += e;
            }
            s += __shfl_xor(s, 1);
            s += __shfl_xor(s, 2);
            s += __shfl_xor(s, 4);
            s += __shfl_xor(s, 8);
            if (l15 == 0) rsum[(ms*16 + lq*4 + i)*4 + w] = s;
        }
    __syncthreads();
    float inv[4][4];
    #pragma unroll
    for (int ms = 0; ms < 4; ++ms)
        #pragma unroll
        for (int i = 0; i < 4; ++i) {
            float4 sv = *(const float4*)&rsum[(ms*16 + lq*4 + i)*4];
            inv[ms][i] = __builtin_amdgcn_rcpf(sv.x + sv.y + sv.z + sv.w);
        }
    // ---- column sums over this block's 64 rows -> partial alpha ----
    float* ap = alphap + ((size_t)b*4 + mblk)*TSEQ;
    #pragma unroll
    for (int g = 0; g < 8; ++g) {
        float c = 0.f;
        #pragma unroll
        for (int ms = 0; ms < 4; ++ms)
            #pragma unroll
            for (int i = 0; i < 4; ++i)
                c = fmaf(acc[ms][g][i], inv[ms][i], c);
        c += __shfl_xor(c, 16);
        c += __shfl_xor(c, 32);
        if (lq == 0) ap[w*128 + g*16 + l15] = c;
    }
}

// ---------------- K4: rep = (sum of 4 partial alphas) @ Hid ; layernorm -> path_feature ----------------
__global__ __launch_bounds__(320)
void k4_rep(const float* __restrict__ alphap, const u16* __restrict__ Hid,
            const float* __restrict__ gamma, const float* __restrict__ beta,
            float* __restrict__ outP)
{
    __shared__ float al[512];
    __shared__ float rs[5], rss[5];
    int tid = threadIdx.x, b = blockIdx.x;
    const float* ap = alphap + (size_t)b*4*TSEQ;
    for (int i = tid; i < 512; i += 320)
        al[i] = ap[i] + ap[512 + i] + ap[1024 + i] + ap[1536 + i];
    __syncthreads();
    float acc = 0.f;
    if (tid < D_HID) {
        const u16* hp = Hid + (size_t)b*TSEQ*320 + tid;
        #pragma unroll 8
        for (int t = 0; t < TSEQ; ++t)
            acc = fmaf(al[t], bf2f(hp[(size_t)t*320]), acc);
    }
    float v = (tid < D_HID) ? acc : 0.f;
    float s = v, q = v*v;
    #pragma unroll
    for (int off = 32; off > 0; off >>= 1) { s += __shfl_xor(s, off, 64); q += __shfl_xor(q, off, 64); }
    if ((tid & 63) == 0) { rs[tid >> 6] = s; rss[tid >> 6] = q; }
    __syncthreads();
    float S = rs[0]+rs[1]+rs[2]+rs[3]+rs[4];
    float Q = rss[0]+rss[1]+rss[2]+rss[3]+rss[4];
    float mu = S * (1.f/300.f);
    float var = Q * (1.f/300.f) - mu*mu;
    if (tid < D_HID)
        outP[(size_t)b*D_HID + tid] = (acc - mu) * rsqrtf(var + 1e-5f) * gamma[tid] + beta[tid];
}

// ---------------- K5: node_feature = nodes @ Wnode^T + bnode via MFMA (fp32 out) ----------------
__global__ __launch_bounds__(256)
void k5_node(const u16* __restrict__ Nbf, const u16* __restrict__ Wnbf,
             const float* __restrict__ bn, float* __restrict__ outN)
{
    __shared__ char smem[16384];
    int tid = threadIdx.x;
    int lane = tid & 63, w = tid >> 6;
    int l15 = lane & 15, lq = lane >> 4;
    int m0 = blockIdx.x * 64;
    int j0w = blockIdx.y*64 + w*16;

    bf16x8 bw[4];
    #pragma unroll
    for (int ks = 0; ks < 4; ++ks)
        bw[ks] = *(const bf16x8*)(Wnbf + ((size_t)(j0w + l15))*128 + ks*32 + lq*8);

    #pragma unroll
    for (int ks = 0; ks < 4; ++ks) {
        const u16* g = Nbf + ((size_t)(m0 + w*16 + l15))*128 + ks*32 + lq*8;
        gload_lds16(g, smem + (size_t)((w*4 + ks)*64)*16);
    }
    __syncthreads();

    f32x4 acc[4];
    #pragma unroll
    for (int ms = 0; ms < 4; ++ms) acc[ms] = (f32x4){0,0,0,0};
    #pragma unroll
    for (int ms = 0; ms < 4; ++ms)
        #pragma unroll
        for (int ks = 0; ks < 4; ++ks) {
            bf16x8 a = *(const bf16x8*)(smem + (size_t)(((ms*4+ks)*64 + lane))*16);
            acc[ms] = __builtin_amdgcn_mfma_f32_16x16x32_bf16(a, bw[ks], acc[ms], 0,0,0);
        }

    int j = j0w + l15;
    if (j < D_HID) {
        float bo = bn[j];
        #pragma unroll
        for (int ms = 0; ms < 4; ++ms)
            #pragma unroll
            for (int i = 0; i < 4; ++i)
                outN[(size_t)(m0 + ms*16 + lq*4 + i)*D_HID + j] = acc[ms][i] + bo;
    }
}

extern "C" void kernel_launch(void* const* d_in, const int* in_sizes, int n_in,
                              void* d_out, int out_size, void* d_ws, size_t ws_size,
                              hipStream_t stream) {
    const float* nodes  = (const float*)d_in[0];
    const float* ctx    = (const float*)d_in[1];
    const int*   trip   = (const int*)d_in[2];
    const float* Wm     = (const float*)d_in[4];
    const float* bm     = (const float*)d_in[5];
    const float* Wihf   = (const float*)d_in[6];
    const float* bihf   = (const float*)d_in[7];
    const float* bhhf   = (const float*)d_in[8];
    const float* Wihb   = (const float*)d_in[9];
    const float* bihb   = (const float*)d_in[10];
    const float* bhhb   = (const float*)d_in[11];
    const float* Wout   = (const float*)d_in[12];
    const float* bout   = (const float*)d_in[13];
    const float* Wnode  = (const float*)d_in[14];
    const float* bnode  = (const float*)d_in[15];
    const float* gamma  = (const float*)d_in[16];
    const float* beta   = (const float*)d_in[17];
    float* out = (float*)d_out;

    char* ws = (char*)d_ws;
    u16*   W4bf   = (u16*)(ws);                         // 491,520 B
    u16*   Woutbf = (u16*)(ws + 491520);                // 466,944 B
    u16*   Wnbf   = (u16*)(ws + 958464);                //  81,920 B
    float* bc     = (float*)(ws + 1040384);             //   7,680 B
    float* bhhn   = (float*)(ws + 1048064);             //   2,560 B
    char*  Hbase  = ws + 1050624;
    u16*   H      = (u16*)Hbase;                        // 79,691,776 B  [65536][608]
    u32*   Cbf    = (u32*)(Hbase + 33554432ull);        // overlay (after k2): 20,971,520 B
    char*  hidbase = Hbase + 79691776ull;               // 80,742,400
    u16*   Hid    = (u16*)hidbase;                      // 41,943,040 B  [65536][320]
    u32*   Abf    = (u32*)hidbase;                      // overlay: 16,777,216 B (dead before k2)
    u32*   Nbf    = (u32*)(hidbase + 16777216ull);      // overlay:  8,388,608 B (dead before k2)
    float* alphap = (float*)(ws + 122685440ull);        // 1,048,576 B -> total 123,734,016 B

    k0_prep<<<dim3(320,3,2), 128, 0, stream>>>(Wm,bm,Wihf,bihf,bhhf,Wihb,bihb,bhhb,W4bf,bc,bhhn);
    kW     <<<1072, 256, 0, stream>>>(Wout,Wnode,Woutbf,Wnbf);
    kA     <<<384,  256, 0, stream>>>(nodes,trip,Abf,Nbf);
    k1_gru <<<dim3(1024,10), 256, 0, stream>>>((const u16*)Abf,W4bf,bc,bhhn,H);
    k5_node<<<dim3(512,5),   256, 0, stream>>>((const u16*)Nbf,Wnbf,bnode,out + 38400);   // before k2 (overlay!)
    k2_out <<<dim3(1024,3),  256, 0, stream>>>(H,Woutbf,bout,Hid);
    kC     <<<20480, 256, 0, stream>>>(ctx, Cbf);                                          // after k2 (overlay!)
    k3_attn<<<dim3(4,128),   256, 0, stream>>>((const u16*)Cbf, Hid, alphap);
    k4_rep <<<128,           320, 0, stream>>>(alphap,Hid,gamma,beta,out);
    hipMemsetAsync(out + 38400 + 9830400, 0, 32768*sizeof(float), stream);
}